// Round 15
// baseline (306.158 us; speedup 1.0000x reference)
//
#include <hip/hip_runtime.h>

#define IN_DIM 128
#define HID 32
#define HEADS 8
#define HC 256          // HEADS*HID
#define N_GRAPHS 64
#define N_CLASSES 10

#define SCAN_ELEMS 8
#define SCAN_BLOCK 256
#define SCAN_CHUNK (SCAN_ELEMS * SCAN_BLOCK)   // 2048 elements per block

typedef __attribute__((ext_vector_type(8))) short bf16x8;
typedef __attribute__((ext_vector_type(4))) float f32x4;

__device__ __forceinline__ float leaky(float v) { return v > 0.f ? v : 0.2f * v; }

// monotone float<->uint encoding for atomicMax on floats
__device__ __forceinline__ unsigned fenc(float f) {
    unsigned u = __float_as_uint(f);
    return (u & 0x80000000u) ? ~u : (u | 0x80000000u);
}
__device__ __forceinline__ float fdec(unsigned u) {
    return __uint_as_float((u & 0x80000000u) ? (u & 0x7FFFFFFFu) : ~u);
}
// bf16 round-to-nearest-even encode / decode
__device__ __forceinline__ unsigned short bf16r(float f) {
    unsigned u = __float_as_uint(f);
    return (unsigned short)((u + 0x7FFFu + ((u >> 16) & 1u)) >> 16);
}
__device__ __forceinline__ float bdec(unsigned short u) {
    return __uint_as_float(((unsigned)u) << 16);
}

// ---------------- setup: zero deg/gm/gsum/gcnt/counter + bf16 frag-order W prep ----------------
__global__ __launch_bounds__(256) void k_setup(
    int* __restrict__ deg, int N, unsigned* __restrict__ gm,
    float* __restrict__ gsum, float* __restrict__ gcnt, int* __restrict__ counter,
    const float* __restrict__ W, const float* __restrict__ Wrel, const float* __restrict__ Wroot,
    unsigned short* __restrict__ Wb, unsigned short* __restrict__ W2b)
{
    int i = blockIdx.x * 256 + threadIdx.x;
    if (i < N) deg[i] = 0;
    if (i < HEADS) gm[i] = 0u;
    if (i < N_GRAPHS * HID) gsum[i] = 0.f;
    if (i < N_GRAPHS) gcnt[i] = 0.f;
    if (i == 0) *counter = 0;

    if (blockIdx.x < 16) {
        int slot = blockIdx.x * 256 + threadIdx.x;    // 4096 slots (16 ct x 4 ks)
        int lane = slot & 63;
        int ctg  = (slot >> 6) & 15;
        int ks   = slot >> 10;
        int col  = ctg * 16 + (lane & 15);
        int kb   = ks * 32 + (lane >> 4) * 8;
        unsigned short t[8];
#pragma unroll
        for (int j = 0; j < 8; ++j) t[j] = bf16r(W[(size_t)(kb + j) * HC + col]);
        ushort4* dst = (ushort4*)(Wb + (size_t)slot * 8);
        dst[0] = make_ushort4(t[0], t[1], t[2], t[3]);
        dst[1] = make_ushort4(t[4], t[5], t[6], t[7]);
    } else if (blockIdx.x < 24) {
        int slot = (blockIdx.x - 16) * 256 + threadIdx.x;  // 2048 slots (4 ct x 8 ks)
        int lane = slot & 63;
        int ct   = (slot >> 6) & 3;
        int ks   = slot >> 8;
        int col  = ct * 16 + (lane & 15);
        int kb   = ks * 32 + (lane >> 4) * 8;
        const float* src = (col < HID) ? (Wrel + col) : (Wroot + (col - HID));
        unsigned short t[8];
#pragma unroll
        for (int j = 0; j < 8; ++j) t[j] = bf16r(src[(size_t)(kb + j) * HID]);
        ushort4* dst = (ushort4*)(W2b + (size_t)slot * 8);
        dst[0] = make_ushort4(t[0], t[1], t[2], t[3]);
        dst[1] = make_ushort4(t[4], t[5], t[6], t[7]);
    }
}

// ---------------- merged: h = x@gat_W (MFMA, LDS-transposed coalesced store) || deg+rank ----------------
__global__ __launch_bounds__(256) void k_gemm_deg(
    const float* __restrict__ x, const unsigned short* __restrict__ Wb,
    const float* __restrict__ att_s, const float* __restrict__ att_d,
    unsigned short* __restrict__ h, float* __restrict__ a_src, float* __restrict__ a_dst, int N,
    const int* __restrict__ edst, int* __restrict__ deg, unsigned short* __restrict__ rank,
    int E, int gemmBlocks)
{
    __shared__ unsigned short sh[4][16][72];
    if (blockIdx.x >= gemmBlocks) {
        int i = (blockIdx.x - gemmBlocks) * 256 + threadIdx.x;
        if (i < E) rank[i] = (unsigned short)atomicAdd(&deg[edst[i]], 1);
        return;
    }
    int w = threadIdx.x >> 6;
    int lane = threadIdx.x & 63;
    int lrow = lane & 15, lgrp = lane >> 4;
    int nb = blockIdx.x * 16;

    int rowc = min(nb + lrow, N - 1);
    const float* xrow = x + (size_t)rowc * IN_DIM + lgrp * 8;

    f32x4 acc0 = {0.f, 0.f, 0.f, 0.f}, acc1 = acc0, acc2 = acc0, acc3 = acc0;

#pragma unroll
    for (int ks = 0; ks < 4; ++ks) {
        float4 a0 = *(const float4*)(xrow + ks * 32);
        float4 a1 = *(const float4*)(xrow + ks * 32 + 4);
        bf16x8 af;
        af[0] = (short)bf16r(a0.x); af[1] = (short)bf16r(a0.y);
        af[2] = (short)bf16r(a0.z); af[3] = (short)bf16r(a0.w);
        af[4] = (short)bf16r(a1.x); af[5] = (short)bf16r(a1.y);
        af[6] = (short)bf16r(a1.z); af[7] = (short)bf16r(a1.w);
        const bf16x8* bp = (const bf16x8*)(Wb + ((size_t)(ks * 16 + w * 4) * 64 + lane) * 8);
        acc0 = __builtin_amdgcn_mfma_f32_16x16x32_bf16(af, bp[0 * 64], acc0, 0, 0, 0);
        acc1 = __builtin_amdgcn_mfma_f32_16x16x32_bf16(af, bp[1 * 64], acc1, 0, 0, 0);
        acc2 = __builtin_amdgcn_mfma_f32_16x16x32_bf16(af, bp[2 * 64], acc2, 0, 0, 0);
        acc3 = __builtin_amdgcn_mfma_f32_16x16x32_bf16(af, bp[3 * 64], acc3, 0, 0, 0);
    }

    int cbase = w * 64;
#pragma unroll
    for (int r = 0; r < 4; ++r) {
        int lr = lgrp * 4 + r;
        sh[w][lr][lrow]      = bf16r(acc0[r]);
        sh[w][lr][16 + lrow] = bf16r(acc1[r]);
        sh[w][lr][32 + lrow] = bf16r(acc2[r]);
        sh[w][lr][48 + lrow] = bf16r(acc3[r]);
    }
#pragma unroll
    for (int round = 0; round < 2; ++round) {
        int row = (lane >> 3) + round * 8;
        int chunk = lane & 7;
        int n = nb + row;
        if (n < N) {
            uint4 t = *(const uint4*)(&sh[w][row][chunk * 8]);
            *(uint4*)(h + (size_t)n * HC + cbase + chunk * 8) = t;
        }
    }
    int h0 = cbase >> 5, h1 = h0 + 1;
    float as00 = att_s[h0 * HID + lrow], as01 = att_s[h0 * HID + 16 + lrow];
    float as10 = att_s[h1 * HID + lrow], as11 = att_s[h1 * HID + 16 + lrow];
    float ad00 = att_d[h0 * HID + lrow], ad01 = att_d[h0 * HID + 16 + lrow];
    float ad10 = att_d[h1 * HID + lrow], ad11 = att_d[h1 * HID + 16 + lrow];
#pragma unroll
    for (int r = 0; r < 4; ++r) {
        float ps0 = acc0[r] * as00 + acc1[r] * as01;
        float pd0 = acc0[r] * ad00 + acc1[r] * ad01;
        float ps1 = acc2[r] * as10 + acc3[r] * as11;
        float pd1 = acc2[r] * ad10 + acc3[r] * ad11;
#pragma unroll
        for (int d = 1; d < 16; d <<= 1) {
            ps0 += __shfl_xor(ps0, d); pd0 += __shfl_xor(pd0, d);
            ps1 += __shfl_xor(ps1, d); pd1 += __shfl_xor(pd1, d);
        }
        int n = nb + lgrp * 4 + r;
        if (lrow == 0 && n < N) {
            a_src[n * HEADS + h0] = ps0; a_dst[n * HEADS + h0] = pd0;
            a_src[n * HEADS + h1] = ps1; a_dst[n * HEADS + h1] = pd1;
        }
    }
}

// ---------------- merged: per-head max of a_src (float4-vectorized) || scan phase-1 partials ----------------
__global__ __launch_bounds__(256) void k_amax_scan(
    const float* __restrict__ asrc, unsigned* __restrict__ gm, int N,
    const int* __restrict__ deg, int* __restrict__ bsum, int amaxBlocks)
{
    int tid = threadIdx.x;
    if (blockIdx.x < amaxBlocks) {
        __shared__ float sm[4][HEADS];
        float m[HEADS];
#pragma unroll
        for (int hh = 0; hh < HEADS; ++hh) m[hh] = -1e30f;
        int stride = amaxBlocks * 256;
        for (int n = blockIdx.x * 256 + tid; n < N; n += stride) {
            float4 p0 = *(const float4*)(asrc + (size_t)n * HEADS);
            float4 p1 = *(const float4*)(asrc + (size_t)n * HEADS + 4);
            m[0] = fmaxf(m[0], p0.x); m[1] = fmaxf(m[1], p0.y);
            m[2] = fmaxf(m[2], p0.z); m[3] = fmaxf(m[3], p0.w);
            m[4] = fmaxf(m[4], p1.x); m[5] = fmaxf(m[5], p1.y);
            m[6] = fmaxf(m[6], p1.z); m[7] = fmaxf(m[7], p1.w);
        }
#pragma unroll
        for (int hh = 0; hh < HEADS; ++hh)
            for (int d = 1; d < 64; d <<= 1) m[hh] = fmaxf(m[hh], __shfl_xor(m[hh], d));
        int lane = tid & 63, wv = tid >> 6;
        if (lane == 0)
#pragma unroll
            for (int hh = 0; hh < HEADS; ++hh) sm[wv][hh] = m[hh];
        __syncthreads();
        if (tid == 0) {
#pragma unroll
            for (int hh = 0; hh < HEADS; ++hh) {
                float mm = fmaxf(fmaxf(sm[0][hh], sm[1][hh]), fmaxf(sm[2][hh], sm[3][hh]));
                atomicMax(&gm[hh], fenc(mm));
            }
        }
    } else {
        int bid = blockIdx.x - amaxBlocks;
        int base = bid * SCAN_CHUNK + tid * SCAN_ELEMS;
        int s = 0;
#pragma unroll
        for (int i = 0; i < SCAN_ELEMS; ++i) { int idx = base + i; if (idx < N) s += deg[idx]; }
#pragma unroll
        for (int d = 1; d < 64; d <<= 1) s += __shfl_xor(s, d);
        __shared__ int ws[4];
        int lane = tid & 63, wv = tid >> 6;
        if (lane == 0) ws[wv] = s;
        __syncthreads();
        if (tid == 0) bsum[bid] = ws[0] + ws[1] + ws[2] + ws[3];
    }
}

// ---------------- scan write: wave-parallel bsum prefix; writes off + off[N] ----------------
__global__ __launch_bounds__(SCAN_BLOCK) void k_scan_write(
    const int* __restrict__ deg, const int* __restrict__ bsum,
    int* __restrict__ off, int N)
{
    __shared__ int sbpre;
    if (threadIdx.x < 64) {
        int lane = threadIdx.x;
        int bv = (lane < (int)blockIdx.x) ? bsum[lane] : 0;
        for (int d = 1; d < 64; d <<= 1) { int t = __shfl_up(bv, d); if (lane >= d) bv += t; }
        if (lane == 63) sbpre = bv;
    }
    int base = blockIdx.x * SCAN_CHUNK + threadIdx.x * SCAN_ELEMS;
    int dl[SCAN_ELEMS];
    int s = 0;
#pragma unroll
    for (int i = 0; i < SCAN_ELEMS; ++i) {
        int idx = base + i;
        dl[i] = (idx < N) ? deg[idx] : 0;
        s += dl[i];
    }
    int lane = threadIdx.x & 63, wv = threadIdx.x >> 6;
    int v = s;
#pragma unroll
    for (int d = 1; d < 64; d <<= 1) { int t = __shfl_up(v, d); if (lane >= d) v += t; }
    __shared__ int ws[4];
    if (lane == 63) ws[wv] = v;
    __syncthreads();
    int wadd = 0;
    for (int w = 0; w < wv; ++w) wadd += ws[w];
    int run = sbpre + wadd + (v - s);
#pragma unroll
    for (int i = 0; i < SCAN_ELEMS; ++i) {
        int idx = base + i;
        if (idx < N) {
            off[idx] = run;
            run += dl[i];
            if (idx == N - 1) off[N] = run;
        }
    }
}

// ---------------- scatter: pos = off[dst] + rank  (NO atomics) ----------------
__global__ void k_scatter(const int* __restrict__ src, const int* __restrict__ dst,
                          const unsigned short* __restrict__ rank, const int* __restrict__ off,
                          unsigned short* __restrict__ srcs, int E) {
    int i = blockIdx.x * blockDim.x + threadIdx.x;
    if (i < E) srcs[off[dst[i]] + (int)rank[i]] = (unsigned short)src[i];
}

// ---------------- FUSED GAT + zr2: x1 lives only in LDS ----------------
// block = 16 nodes, 4 waves x 4 nodes serially; x1 rows -> sx1[16][264] (264-pad:
// row stride 132 dwords = 4 banks -> <=2-way conflicts, free); one barrier; then the
// verbatim zr2 MFMA phase (K=256 from LDS). Eliminates x1 buffer (12.8MB traffic) + 1 launch.
// Launched over node ranges [n0,n1) (16-aligned) for top-5 visibility (~28us threshold).
__global__ __launch_bounds__(256) void k_gat_zr(
    const unsigned short* __restrict__ h, const float* __restrict__ asrc, const float* __restrict__ adst,
    const float* __restrict__ bias, const int* __restrict__ off, const unsigned short* __restrict__ srcs,
    const unsigned* __restrict__ gm, const unsigned short* __restrict__ W2b,
    unsigned short* __restrict__ z, float* __restrict__ r, int n0, int n1, int N)
{
    __shared__ unsigned short sx1[16][264];
    int w = threadIdx.x >> 6;
    int lane = threadIdx.x & 63;
    int nb = n0 + blockIdx.x * 16;
    int head = lane >> 3;
    int c = lane * 4;
    float4 b4 = *(const float4*)(bias + c);
    float gmh = fdec(gm[head]);

    for (int t = 0; t < 4; ++t) {
        int v = min(nb + w * 4 + t, N - 1);
        float ad = adst[v * HEADS + head];
        float asv = asrc[v * HEADS + head];
        float m = leaky(gmh + ad);
        int beg = off[v], end = off[v + 1];

        ushort4 hv = *(const ushort4*)(h + (size_t)v * HC + c);
        float wg = __expf(leaky(asv + ad) - m);
        float zz = wg;
        float acc0 = wg * bdec(hv.x), acc1 = wg * bdec(hv.y), acc2 = wg * bdec(hv.z), acc3 = wg * bdec(hv.w);

        int e = beg;
        for (; e + 4 <= end; e += 4) {
            int s0 = srcs[e + 0], s1 = srcs[e + 1], s2 = srcs[e + 2], s3 = srcs[e + 3];
            float l0 = asrc[s0 * HEADS + head], l1 = asrc[s1 * HEADS + head];
            float l2 = asrc[s2 * HEADS + head], l3 = asrc[s3 * HEADS + head];
            ushort4 g0 = *(const ushort4*)(h + (size_t)s0 * HC + c);
            ushort4 g1 = *(const ushort4*)(h + (size_t)s1 * HC + c);
            ushort4 g2 = *(const ushort4*)(h + (size_t)s2 * HC + c);
            ushort4 g3 = *(const ushort4*)(h + (size_t)s3 * HC + c);
            float w0 = __expf(leaky(l0 + ad) - m);
            float w1 = __expf(leaky(l1 + ad) - m);
            float w2 = __expf(leaky(l2 + ad) - m);
            float w3 = __expf(leaky(l3 + ad) - m);
            zz += (w0 + w1) + (w2 + w3);
            acc0 += w0 * bdec(g0.x) + w1 * bdec(g1.x) + w2 * bdec(g2.x) + w3 * bdec(g3.x);
            acc1 += w0 * bdec(g0.y) + w1 * bdec(g1.y) + w2 * bdec(g2.y) + w3 * bdec(g3.y);
            acc2 += w0 * bdec(g0.z) + w1 * bdec(g1.z) + w2 * bdec(g2.z) + w3 * bdec(g3.z);
            acc3 += w0 * bdec(g0.w) + w1 * bdec(g1.w) + w2 * bdec(g2.w) + w3 * bdec(g3.w);
        }
        for (; e < end; ++e) {
            int s = srcs[e];
            float we = __expf(leaky(asrc[s * HEADS + head] + ad) - m);
            ushort4 hs = *(const ushort4*)(h + (size_t)s * HC + c);
            zz += we;
            acc0 += we * bdec(hs.x); acc1 += we * bdec(hs.y);
            acc2 += we * bdec(hs.z); acc3 += we * bdec(hs.w);
        }
        float inv_z = 1.f / (zz + 1e-16f);
        ushort4 o;
        o.x = bf16r(fmaxf(acc0 * inv_z + b4.x, 0.f));
        o.y = bf16r(fmaxf(acc1 * inv_z + b4.y, 0.f));
        o.z = bf16r(fmaxf(acc2 * inv_z + b4.z, 0.f));
        o.w = bf16r(fmaxf(acc3 * inv_z + b4.w, 0.f));
        *(ushort4*)(&sx1[w * 4 + t][c]) = o;
    }
    __syncthreads();

    // ---- zr2 phase (verbatim k_zr2, A-frag from LDS) ----
    int lrow = lane & 15, lgrp = lane >> 4;
    f32x4 acc = {0.f, 0.f, 0.f, 0.f};
#pragma unroll
    for (int ks = 0; ks < 8; ++ks) {
        bf16x8 af = *(const bf16x8*)(&sx1[lrow][ks * 32 + lgrp * 8]);
        const bf16x8* bp = (const bf16x8*)(W2b + ((size_t)(ks * 4 + w) * 64 + lane) * 8);
        acc = __builtin_amdgcn_mfma_f32_16x16x32_bf16(af, *bp, acc, 0, 0, 0);
    }
    int col = w * 16 + lrow;
#pragma unroll
    for (int rr = 0; rr < 4; ++rr) {
        int n = nb + lgrp * 4 + rr;
        if (n < n1) {
            if (col < HID) z[(size_t)n * HID + col] = bf16r(acc[rr]);
            else           r[(size_t)n * HID + (col - HID)] = acc[rr];
        }
    }
}

// ---------------- x2 = relu(sum_j z[j] + r[v] + b2)  (32-wide bf16 gather, 4x ILP) ----------------
__global__ __launch_bounds__(256) void k_agg_lin(
    const unsigned short* __restrict__ z, const float* __restrict__ r, const float* __restrict__ b,
    const int* __restrict__ off, const unsigned short* __restrict__ srcs,
    unsigned short* __restrict__ xout, int N)
{
    int nl = threadIdx.x >> 5, j = threadIdx.x & 31;
    int n = blockIdx.x * 8 + nl;
    if (n >= N) return;
    float acc = r[n * HID + j] + b[j];
    int beg = off[n], end = off[n + 1];
    int e = beg;
    for (; e + 4 <= end; e += 4) {
        int s0 = srcs[e], s1 = srcs[e + 1], s2 = srcs[e + 2], s3 = srcs[e + 3];
        float v0 = bdec(z[s0 * HID + j]);
        float v1 = bdec(z[s1 * HID + j]);
        float v2 = bdec(z[s2 * HID + j]);
        float v3 = bdec(z[s3 * HID + j]);
        acc += (v0 + v1) + (v2 + v3);
    }
    for (; e < end; ++e)
        acc += bdec(z[srcs[e] * HID + j]);
    xout[n * HID + j] = bf16r(fmaxf(acc, 0.f));
}

// ---------------- fused 32-wide conv (bf16 in/out): agg (4x ILP) + two 32x32 GEMMs + relu ----------------
template <bool MEAN>
__global__ __launch_bounds__(256) void k_conv32(
    const unsigned short* __restrict__ xin, const int* __restrict__ off, const unsigned short* __restrict__ srcs,
    const float* __restrict__ Wl, const float* __restrict__ Wr, const float* __restrict__ b,
    unsigned short* __restrict__ xout, int N)
{
    __shared__ float sagg[8][HID];
    __shared__ float sx[8][HID];
    int nl = threadIdx.x >> 5, j = threadIdx.x & 31;
    int n = blockIdx.x * 8 + nl;
    int nc = min(n, N - 1);
    int beg = off[nc], end = off[nc + 1];
    float acc = 0.f;
    int e = beg;
    for (; e + 4 <= end; e += 4) {
        int s0 = srcs[e], s1 = srcs[e + 1], s2 = srcs[e + 2], s3 = srcs[e + 3];
        float v0 = bdec(xin[s0 * HID + j]);
        float v1 = bdec(xin[s1 * HID + j]);
        float v2 = bdec(xin[s2 * HID + j]);
        float v3 = bdec(xin[s3 * HID + j]);
        acc += (v0 + v1) + (v2 + v3);
    }
    for (; e < end; ++e)
        acc += bdec(xin[srcs[e] * HID + j]);
    if (MEAN) acc /= fmaxf((float)(end - beg), 1.f);
    sagg[nl][j] = acc;
    sx[nl][j] = bdec(xin[nc * HID + j]);
    __syncthreads();
    float o = b[j];
#pragma unroll
    for (int k = 0; k < HID; ++k)
        o += sagg[nl][k] * Wl[k * HID + j] + sx[nl][k] * Wr[k * HID + j];
    o = fmaxf(o, 0.f);
    if (n < N) xout[n * HID + j] = bf16r(o);
}

// ---------------- pool (run-accumulate, PER_BLOCK=128) + last-block MLP head ----------------
__global__ __launch_bounds__(256) void k_pool_head(
    const unsigned short* __restrict__ x4, const int* __restrict__ batch,
    float* __restrict__ gsum, float* __restrict__ gcnt, int N, int* __restrict__ counter,
    const float* __restrict__ fc1W, const float* __restrict__ fc1b,
    const float* __restrict__ fc2W, const float* __restrict__ fc2b,
    float* __restrict__ out)
{
    const int PER_BLOCK = 128;
    int base = blockIdx.x * PER_BLOCK;
    int endn = min(base + PER_BLOCK, N);
    int c = threadIdx.x & 31, no = threadIdx.x >> 5;
    {
        float acc = 0.f, cnt = 0.f;
        int curg = -1;
        for (int n = base + no; n < endn; n += 8) {
            int g = batch[n];
            if (g != curg) {
                if (curg >= 0) {
                    atomicAdd(&gsum[curg * HID + c], acc);
                    if (c == 0) atomicAdd(&gcnt[curg], cnt);
                }
                curg = g; acc = 0.f; cnt = 0.f;
            }
            acc += bdec(x4[n * HID + c]);
            cnt += 1.f;
        }
        if (curg >= 0) {
            atomicAdd(&gsum[curg * HID + c], acc);
            if (c == 0) atomicAdd(&gcnt[curg], cnt);
        }
    }
    __threadfence();
    __shared__ int lastFlag;
    if (threadIdx.x == 0) lastFlag = (atomicAdd(counter, 1) == (int)gridDim.x - 1);
    __syncthreads();
    if (!lastFlag) return;

    __shared__ float g[N_GRAPHS * HID];
    __shared__ float t[N_GRAPHS * HID];
    __shared__ float gc[N_GRAPHS];
    int tid = threadIdx.x;
    if (tid < N_GRAPHS) gc[tid] = atomicAdd(&gcnt[tid], 0.f);
    __syncthreads();
    for (int i = tid; i < N_GRAPHS * HID; i += 256)
        g[i] = atomicAdd(&gsum[i], 0.f) / fmaxf(gc[i >> 5], 1.f);
    __syncthreads();
    for (int i = tid; i < N_GRAPHS * HID; i += 256) {
        int gi = i >> 5, j = i & 31;
        float o = fc1b[j];
#pragma unroll
        for (int k = 0; k < HID; ++k) o += g[gi * HID + k] * fc1W[k * HID + j];
        t[i] = fmaxf(o, 0.f);
    }
    __syncthreads();
    for (int i = tid; i < N_GRAPHS * N_CLASSES; i += 256) {
        int gi = i / N_CLASSES, j = i % N_CLASSES;
        float o = fc2b[j];
#pragma unroll
        for (int k = 0; k < HID; ++k) o += t[gi * HID + k] * fc2W[k * N_CLASSES + j];
        out[i] = o;
    }
}

extern "C" void kernel_launch(void* const* d_in, const int* in_sizes, int n_in,
                              void* d_out, int out_size, void* d_ws, size_t ws_size,
                              hipStream_t stream)
{
    const float* x       = (const float*)d_in[0];
    const int*   eidx    = (const int*)d_in[1];
    const int*   batch   = (const int*)d_in[2];
    const float* gat_W   = (const float*)d_in[3];
    const float* att_s   = (const float*)d_in[4];
    const float* att_d   = (const float*)d_in[5];
    const float* gat_b   = (const float*)d_in[6];
    const float* W2_rel  = (const float*)d_in[7];
    const float* b2      = (const float*)d_in[8];
    const float* W2_root = (const float*)d_in[9];
    const float* W3_l    = (const float*)d_in[10];
    const float* b3      = (const float*)d_in[11];
    const float* W3_r    = (const float*)d_in[12];
    const float* W4_rel  = (const float*)d_in[13];
    const float* b4      = (const float*)d_in[14];
    const float* W4_root = (const float*)d_in[15];
    const float* fc1_W   = (const float*)d_in[16];
    const float* fc1_b   = (const float*)d_in[17];
    const float* fc2_W   = (const float*)d_in[18];
    const float* fc2_b   = (const float*)d_in[19];

    const int N = in_sizes[2];
    const int E = in_sizes[1] / 2;
    const int* esrc = eidx;
    const int* edst = eidx + E;

    char* wsb = (char*)d_ws;
    size_t ofs = 0;
    auto alloc = [&](size_t bytes) {
        char* p = wsb + ofs;
        ofs = (ofs + bytes + 255) & ~(size_t)255;
        return p;
    };
    unsigned short* h   = (unsigned short*)alloc((size_t)N * HC * 2);
    unsigned short* Wb  = (unsigned short*)alloc((size_t)IN_DIM * HC * 2);
    unsigned short* W2b = (unsigned short*)alloc((size_t)HC * 64 * 2);
    float* a_src = (float*)alloc((size_t)N * HEADS * 4);
    float* a_dst = (float*)alloc((size_t)N * HEADS * 4);
    int*   deg   = (int*)alloc((size_t)N * 4);
    int*   off   = (int*)alloc((size_t)(N + 1) * 4);
    unsigned short* rank = (unsigned short*)alloc((size_t)E * 2);
    unsigned short* srcs = (unsigned short*)alloc((size_t)E * 2);
    int*   bsum  = (int*)alloc((size_t)128 * 4);
    unsigned short* zb  = (unsigned short*)alloc((size_t)N * HID * 2);
    float* r     = (float*)alloc((size_t)N * HID * 4);
    unsigned short* x2b = (unsigned short*)alloc((size_t)N * HID * 2);
    unsigned short* x3b = (unsigned short*)alloc((size_t)N * HID * 2);
    unsigned short* x4b = (unsigned short*)alloc((size_t)N * HID * 2);
    float* gsum  = (float*)alloc(N_GRAPHS * HID * 4);
    float* gcnt  = (float*)alloc(N_GRAPHS * 4);
    unsigned* gm = (unsigned*)alloc(HEADS * 4);
    int*  counter = (int*)alloc(4);
    (void)ws_size; (void)n_in; (void)out_size;

    const int nscan = (N + SCAN_CHUNK - 1) / SCAN_CHUNK;
    const int gemmBlocks = (N + 15) / 16;
    const int degBlocks  = (E + 255) / 256;
    const int amaxBlocks = 128;
    const int poolBlocks = (N + 127) / 128;
    // 3-way node split on 16-aligned boundaries (instrumentation: top-5 threshold ~1/3)
    int t1 = ((N / 3 + 15) / 16) * 16;       if (t1 > N) t1 = N;
    int t2 = ((2 * N / 3 + 15) / 16) * 16;   if (t2 > N) t2 = N;

    k_setup<<<(N + 255) / 256, 256, 0, stream>>>(deg, N, gm, gsum, gcnt, counter,
                                                 gat_W, W2_rel, W2_root, Wb, W2b);
    k_gemm_deg<<<gemmBlocks + degBlocks, 256, 0, stream>>>(
        x, Wb, att_s, att_d, h, a_src, a_dst, N, edst, deg, rank, E, gemmBlocks);
    k_amax_scan<<<amaxBlocks + nscan, 256, 0, stream>>>(a_src, gm, N, deg, bsum, amaxBlocks);
    k_scan_write<<<nscan, SCAN_BLOCK, 0, stream>>>(deg, bsum, off, N);
    k_scatter<<<(E + 255) / 256, 256, 0, stream>>>(esrc, edst, rank, off, srcs, E);
    k_gat_zr<<<t1 / 16, 256, 0, stream>>>(h, a_src, a_dst, gat_b, off, srcs, gm, W2b, zb, r, 0, t1, N);
    k_gat_zr<<<(t2 - t1) / 16, 256, 0, stream>>>(h, a_src, a_dst, gat_b, off, srcs, gm, W2b, zb, r, t1, t2, N);
    k_gat_zr<<<(N - t2 + 15) / 16, 256, 0, stream>>>(h, a_src, a_dst, gat_b, off, srcs, gm, W2b, zb, r, t2, N, N);
    k_agg_lin<<<(N + 7) / 8, 256, 0, stream>>>(zb, r, b2, off, srcs, x2b, N);
    k_conv32<true><<<(N + 7) / 8, 256, 0, stream>>>(x2b, off, srcs, W3_l, W3_r, b3, x3b, N);
    k_conv32<false><<<(N + 7) / 8, 256, 0, stream>>>(x3b, off, srcs, W4_rel, W4_root, b4, x4b, N);
    k_pool_head<<<poolBlocks, 256, 0, stream>>>(x4b, batch, gsum, gcnt, N, counter,
                                                fc1_W, fc1_b, fc2_W, fc2_b, (float*)d_out);
}

// Round 16
// 285.642 us; speedup vs baseline: 1.0718x; 1.0718x over previous
//
#include <hip/hip_runtime.h>

#define IN_DIM 128
#define HID 32
#define HEADS 8
#define HC 256          // HEADS*HID
#define N_GRAPHS 64
#define N_CLASSES 10

#define SCAN_ELEMS 8
#define SCAN_BLOCK 256
#define SCAN_CHUNK (SCAN_ELEMS * SCAN_BLOCK)   // 2048 elements per block

typedef __attribute__((ext_vector_type(8))) short bf16x8;
typedef __attribute__((ext_vector_type(4))) float f32x4;

__device__ __forceinline__ float leaky(float v) { return v > 0.f ? v : 0.2f * v; }

// monotone float<->uint encoding for atomicMax on floats
__device__ __forceinline__ unsigned fenc(float f) {
    unsigned u = __float_as_uint(f);
    return (u & 0x80000000u) ? ~u : (u | 0x80000000u);
}
__device__ __forceinline__ float fdec(unsigned u) {
    return __uint_as_float((u & 0x80000000u) ? (u & 0x7FFFFFFFu) : ~u);
}
// bf16 round-to-nearest-even encode / decode
__device__ __forceinline__ unsigned short bf16r(float f) {
    unsigned u = __float_as_uint(f);
    return (unsigned short)((u + 0x7FFFu + ((u >> 16) & 1u)) >> 16);
}
__device__ __forceinline__ float bdec(unsigned short u) {
    return __uint_as_float(((unsigned)u) << 16);
}

// ---------------- setup: zero deg/gm/gsum/gcnt/counter + bf16 frag-order W prep ----------------
__global__ __launch_bounds__(256) void k_setup(
    int* __restrict__ deg, int N, unsigned* __restrict__ gm,
    float* __restrict__ gsum, float* __restrict__ gcnt, int* __restrict__ counter,
    const float* __restrict__ W, const float* __restrict__ Wrel, const float* __restrict__ Wroot,
    unsigned short* __restrict__ Wb, unsigned short* __restrict__ W2b)
{
    int i = blockIdx.x * 256 + threadIdx.x;
    if (i < N) deg[i] = 0;
    if (i < HEADS) gm[i] = 0u;
    if (i < N_GRAPHS * HID) gsum[i] = 0.f;
    if (i < N_GRAPHS) gcnt[i] = 0.f;
    if (i == 0) *counter = 0;

    if (blockIdx.x < 16) {
        int slot = blockIdx.x * 256 + threadIdx.x;    // 4096 slots (16 ct x 4 ks)
        int lane = slot & 63;
        int ctg  = (slot >> 6) & 15;
        int ks   = slot >> 10;
        int col  = ctg * 16 + (lane & 15);
        int kb   = ks * 32 + (lane >> 4) * 8;
        unsigned short t[8];
#pragma unroll
        for (int j = 0; j < 8; ++j) t[j] = bf16r(W[(size_t)(kb + j) * HC + col]);
        ushort4* dst = (ushort4*)(Wb + (size_t)slot * 8);
        dst[0] = make_ushort4(t[0], t[1], t[2], t[3]);
        dst[1] = make_ushort4(t[4], t[5], t[6], t[7]);
    } else if (blockIdx.x < 24) {
        int slot = (blockIdx.x - 16) * 256 + threadIdx.x;  // 2048 slots (4 ct x 8 ks)
        int lane = slot & 63;
        int ct   = (slot >> 6) & 3;
        int ks   = slot >> 8;
        int col  = ct * 16 + (lane & 15);
        int kb   = ks * 32 + (lane >> 4) * 8;
        const float* src = (col < HID) ? (Wrel + col) : (Wroot + (col - HID));
        unsigned short t[8];
#pragma unroll
        for (int j = 0; j < 8; ++j) t[j] = bf16r(src[(size_t)(kb + j) * HID]);
        ushort4* dst = (ushort4*)(W2b + (size_t)slot * 8);
        dst[0] = make_ushort4(t[0], t[1], t[2], t[3]);
        dst[1] = make_ushort4(t[4], t[5], t[6], t[7]);
    }
}

// ---------------- merged: h = x@gat_W (MFMA, LDS-staged A-tile) || deg+rank ----------------
// x-tile staged via coalesced fp32 loads -> bf16 LDS (was: 16-row-strided 16B chunks,
// 4x redundant across waves -> latency-bound 60us at 9% VALU).
__global__ __launch_bounds__(256) void k_gemm_deg(
    const float* __restrict__ x, const unsigned short* __restrict__ Wb,
    const float* __restrict__ att_s, const float* __restrict__ att_d,
    unsigned short* __restrict__ h, float* __restrict__ a_src, float* __restrict__ a_dst, int N,
    const int* __restrict__ edst, int* __restrict__ deg, unsigned short* __restrict__ rank,
    int E, int gemmBlocks)
{
    __shared__ unsigned short sxt[16][136];   // bf16 A-tile, 8-ushort pad (<=2-way conflicts)
    __shared__ unsigned short sh[4][16][72];  // output transpose staging
    if (blockIdx.x >= gemmBlocks) {
        int i = (blockIdx.x - gemmBlocks) * 256 + threadIdx.x;
        if (i < E) rank[i] = (unsigned short)atomicAdd(&deg[edst[i]], 1);
        return;
    }
    int w = threadIdx.x >> 6;
    int lane = threadIdx.x & 63;
    int lrow = lane & 15, lgrp = lane >> 4;
    int nb = blockIdx.x * 16;

    // stage: 16 threads per row, 8 floats each -> fully coalesced 512B row reads, bf16 once
    {
        int row = threadIdx.x >> 4, col = (threadIdx.x & 15) * 8;
        int n = min(nb + row, N - 1);
        const float* xp = x + (size_t)n * IN_DIM + col;
        float4 a0 = *(const float4*)xp;
        float4 a1 = *(const float4*)(xp + 4);
        *(ushort4*)(&sxt[row][col])     = make_ushort4(bf16r(a0.x), bf16r(a0.y), bf16r(a0.z), bf16r(a0.w));
        *(ushort4*)(&sxt[row][col + 4]) = make_ushort4(bf16r(a1.x), bf16r(a1.y), bf16r(a1.z), bf16r(a1.w));
    }
    __syncthreads();

    f32x4 acc0 = {0.f, 0.f, 0.f, 0.f}, acc1 = acc0, acc2 = acc0, acc3 = acc0;

#pragma unroll
    for (int ks = 0; ks < 4; ++ks) {
        bf16x8 af = *(const bf16x8*)(&sxt[lrow][ks * 32 + lgrp * 8]);
        const bf16x8* bp = (const bf16x8*)(Wb + ((size_t)(ks * 16 + w * 4) * 64 + lane) * 8);
        acc0 = __builtin_amdgcn_mfma_f32_16x16x32_bf16(af, bp[0 * 64], acc0, 0, 0, 0);
        acc1 = __builtin_amdgcn_mfma_f32_16x16x32_bf16(af, bp[1 * 64], acc1, 0, 0, 0);
        acc2 = __builtin_amdgcn_mfma_f32_16x16x32_bf16(af, bp[2 * 64], acc2, 0, 0, 0);
        acc3 = __builtin_amdgcn_mfma_f32_16x16x32_bf16(af, bp[3 * 64], acc3, 0, 0, 0);
    }

    int cbase = w * 64;
#pragma unroll
    for (int r = 0; r < 4; ++r) {
        int lr = lgrp * 4 + r;
        sh[w][lr][lrow]      = bf16r(acc0[r]);
        sh[w][lr][16 + lrow] = bf16r(acc1[r]);
        sh[w][lr][32 + lrow] = bf16r(acc2[r]);
        sh[w][lr][48 + lrow] = bf16r(acc3[r]);
    }
#pragma unroll
    for (int round = 0; round < 2; ++round) {
        int row = (lane >> 3) + round * 8;
        int chunk = lane & 7;
        int n = nb + row;
        if (n < N) {
            uint4 t = *(const uint4*)(&sh[w][row][chunk * 8]);
            *(uint4*)(h + (size_t)n * HC + cbase + chunk * 8) = t;
        }
    }
    int h0 = cbase >> 5, h1 = h0 + 1;
    float as00 = att_s[h0 * HID + lrow], as01 = att_s[h0 * HID + 16 + lrow];
    float as10 = att_s[h1 * HID + lrow], as11 = att_s[h1 * HID + 16 + lrow];
    float ad00 = att_d[h0 * HID + lrow], ad01 = att_d[h0 * HID + 16 + lrow];
    float ad10 = att_d[h1 * HID + lrow], ad11 = att_d[h1 * HID + 16 + lrow];
#pragma unroll
    for (int r = 0; r < 4; ++r) {
        float ps0 = acc0[r] * as00 + acc1[r] * as01;
        float pd0 = acc0[r] * ad00 + acc1[r] * ad01;
        float ps1 = acc2[r] * as10 + acc3[r] * as11;
        float pd1 = acc2[r] * ad10 + acc3[r] * ad11;
#pragma unroll
        for (int d = 1; d < 16; d <<= 1) {
            ps0 += __shfl_xor(ps0, d); pd0 += __shfl_xor(pd0, d);
            ps1 += __shfl_xor(ps1, d); pd1 += __shfl_xor(pd1, d);
        }
        int n = nb + lgrp * 4 + r;
        if (lrow == 0 && n < N) {
            a_src[n * HEADS + h0] = ps0; a_dst[n * HEADS + h0] = pd0;
            a_src[n * HEADS + h1] = ps1; a_dst[n * HEADS + h1] = pd1;
        }
    }
}

// ---------------- merged: per-head max of a_src (float4-vectorized) || scan phase-1 partials ----------------
__global__ __launch_bounds__(256) void k_amax_scan(
    const float* __restrict__ asrc, unsigned* __restrict__ gm, int N,
    const int* __restrict__ deg, int* __restrict__ bsum, int amaxBlocks)
{
    int tid = threadIdx.x;
    if (blockIdx.x < amaxBlocks) {
        __shared__ float sm[4][HEADS];
        float m[HEADS];
#pragma unroll
        for (int hh = 0; hh < HEADS; ++hh) m[hh] = -1e30f;
        int stride = amaxBlocks * 256;
        for (int n = blockIdx.x * 256 + tid; n < N; n += stride) {
            float4 p0 = *(const float4*)(asrc + (size_t)n * HEADS);
            float4 p1 = *(const float4*)(asrc + (size_t)n * HEADS + 4);
            m[0] = fmaxf(m[0], p0.x); m[1] = fmaxf(m[1], p0.y);
            m[2] = fmaxf(m[2], p0.z); m[3] = fmaxf(m[3], p0.w);
            m[4] = fmaxf(m[4], p1.x); m[5] = fmaxf(m[5], p1.y);
            m[6] = fmaxf(m[6], p1.z); m[7] = fmaxf(m[7], p1.w);
        }
#pragma unroll
        for (int hh = 0; hh < HEADS; ++hh)
            for (int d = 1; d < 64; d <<= 1) m[hh] = fmaxf(m[hh], __shfl_xor(m[hh], d));
        int lane = tid & 63, wv = tid >> 6;
        if (lane == 0)
#pragma unroll
            for (int hh = 0; hh < HEADS; ++hh) sm[wv][hh] = m[hh];
        __syncthreads();
        if (tid == 0) {
#pragma unroll
            for (int hh = 0; hh < HEADS; ++hh) {
                float mm = fmaxf(fmaxf(sm[0][hh], sm[1][hh]), fmaxf(sm[2][hh], sm[3][hh]));
                atomicMax(&gm[hh], fenc(mm));
            }
        }
    } else {
        int bid = blockIdx.x - amaxBlocks;
        int base = bid * SCAN_CHUNK + tid * SCAN_ELEMS;
        int s = 0;
#pragma unroll
        for (int i = 0; i < SCAN_ELEMS; ++i) { int idx = base + i; if (idx < N) s += deg[idx]; }
#pragma unroll
        for (int d = 1; d < 64; d <<= 1) s += __shfl_xor(s, d);
        __shared__ int ws[4];
        int lane = tid & 63, wv = tid >> 6;
        if (lane == 0) ws[wv] = s;
        __syncthreads();
        if (tid == 0) bsum[bid] = ws[0] + ws[1] + ws[2] + ws[3];
    }
}

// ---------------- scan write: wave-parallel bsum prefix; writes off + off[N] ----------------
__global__ __launch_bounds__(SCAN_BLOCK) void k_scan_write(
    const int* __restrict__ deg, const int* __restrict__ bsum,
    int* __restrict__ off, int N)
{
    __shared__ int sbpre;
    if (threadIdx.x < 64) {
        int lane = threadIdx.x;
        int bv = (lane < (int)blockIdx.x) ? bsum[lane] : 0;
        for (int d = 1; d < 64; d <<= 1) { int t = __shfl_up(bv, d); if (lane >= d) bv += t; }
        if (lane == 63) sbpre = bv;
    }
    int base = blockIdx.x * SCAN_CHUNK + threadIdx.x * SCAN_ELEMS;
    int dl[SCAN_ELEMS];
    int s = 0;
#pragma unroll
    for (int i = 0; i < SCAN_ELEMS; ++i) {
        int idx = base + i;
        dl[i] = (idx < N) ? deg[idx] : 0;
        s += dl[i];
    }
    int lane = threadIdx.x & 63, wv = threadIdx.x >> 6;
    int v = s;
#pragma unroll
    for (int d = 1; d < 64; d <<= 1) { int t = __shfl_up(v, d); if (lane >= d) v += t; }
    __shared__ int ws[4];
    if (lane == 63) ws[wv] = v;
    __syncthreads();
    int wadd = 0;
    for (int w = 0; w < wv; ++w) wadd += ws[w];
    int run = sbpre + wadd + (v - s);
#pragma unroll
    for (int i = 0; i < SCAN_ELEMS; ++i) {
        int idx = base + i;
        if (idx < N) {
            off[idx] = run;
            run += dl[i];
            if (idx == N - 1) off[N] = run;
        }
    }
}

// ---------------- scatter: pos = off[dst] + rank  (NO atomics) ----------------
__global__ void k_scatter(const int* __restrict__ src, const int* __restrict__ dst,
                          const unsigned short* __restrict__ rank, const int* __restrict__ off,
                          unsigned short* __restrict__ srcs, int E) {
    int i = blockIdx.x * blockDim.x + threadIdx.x;
    if (i < E) srcs[off[dst[i]] + (int)rank[i]] = (unsigned short)src[i];
}

// ---------------- FUSED GAT + zr2: x1 lives only in LDS (single launch) ----------------
__global__ __launch_bounds__(256) void k_gat_zr(
    const unsigned short* __restrict__ h, const float* __restrict__ asrc, const float* __restrict__ adst,
    const float* __restrict__ bias, const int* __restrict__ off, const unsigned short* __restrict__ srcs,
    const unsigned* __restrict__ gm, const unsigned short* __restrict__ W2b,
    unsigned short* __restrict__ z, float* __restrict__ r, int N)
{
    __shared__ unsigned short sx1[16][264];
    int w = threadIdx.x >> 6;
    int lane = threadIdx.x & 63;
    int nb = blockIdx.x * 16;
    int head = lane >> 3;
    int c = lane * 4;
    float4 b4 = *(const float4*)(bias + c);
    float gmh = fdec(gm[head]);

    for (int t = 0; t < 4; ++t) {
        int v = min(nb + w * 4 + t, N - 1);
        float ad = adst[v * HEADS + head];
        float asv = asrc[v * HEADS + head];
        float m = leaky(gmh + ad);
        int beg = off[v], end = off[v + 1];

        ushort4 hv = *(const ushort4*)(h + (size_t)v * HC + c);
        float wg = __expf(leaky(asv + ad) - m);
        float zz = wg;
        float acc0 = wg * bdec(hv.x), acc1 = wg * bdec(hv.y), acc2 = wg * bdec(hv.z), acc3 = wg * bdec(hv.w);

        int e = beg;
        for (; e + 4 <= end; e += 4) {
            int s0 = srcs[e + 0], s1 = srcs[e + 1], s2 = srcs[e + 2], s3 = srcs[e + 3];
            float l0 = asrc[s0 * HEADS + head], l1 = asrc[s1 * HEADS + head];
            float l2 = asrc[s2 * HEADS + head], l3 = asrc[s3 * HEADS + head];
            ushort4 g0 = *(const ushort4*)(h + (size_t)s0 * HC + c);
            ushort4 g1 = *(const ushort4*)(h + (size_t)s1 * HC + c);
            ushort4 g2 = *(const ushort4*)(h + (size_t)s2 * HC + c);
            ushort4 g3 = *(const ushort4*)(h + (size_t)s3 * HC + c);
            float w0 = __expf(leaky(l0 + ad) - m);
            float w1 = __expf(leaky(l1 + ad) - m);
            float w2 = __expf(leaky(l2 + ad) - m);
            float w3 = __expf(leaky(l3 + ad) - m);
            zz += (w0 + w1) + (w2 + w3);
            acc0 += w0 * bdec(g0.x) + w1 * bdec(g1.x) + w2 * bdec(g2.x) + w3 * bdec(g3.x);
            acc1 += w0 * bdec(g0.y) + w1 * bdec(g1.y) + w2 * bdec(g2.y) + w3 * bdec(g3.y);
            acc2 += w0 * bdec(g0.z) + w1 * bdec(g1.z) + w2 * bdec(g2.z) + w3 * bdec(g3.z);
            acc3 += w0 * bdec(g0.w) + w1 * bdec(g1.w) + w2 * bdec(g2.w) + w3 * bdec(g3.w);
        }
        for (; e < end; ++e) {
            int s = srcs[e];
            float we = __expf(leaky(asrc[s * HEADS + head] + ad) - m);
            ushort4 hs = *(const ushort4*)(h + (size_t)s * HC + c);
            zz += we;
            acc0 += we * bdec(hs.x); acc1 += we * bdec(hs.y);
            acc2 += we * bdec(hs.z); acc3 += we * bdec(hs.w);
        }
        float inv_z = 1.f / (zz + 1e-16f);
        ushort4 o;
        o.x = bf16r(fmaxf(acc0 * inv_z + b4.x, 0.f));
        o.y = bf16r(fmaxf(acc1 * inv_z + b4.y, 0.f));
        o.z = bf16r(fmaxf(acc2 * inv_z + b4.z, 0.f));
        o.w = bf16r(fmaxf(acc3 * inv_z + b4.w, 0.f));
        *(ushort4*)(&sx1[w * 4 + t][c]) = o;
    }
    __syncthreads();

    int lrow = lane & 15, lgrp = lane >> 4;
    f32x4 acc = {0.f, 0.f, 0.f, 0.f};
#pragma unroll
    for (int ks = 0; ks < 8; ++ks) {
        bf16x8 af = *(const bf16x8*)(&sx1[lrow][ks * 32 + lgrp * 8]);
        const bf16x8* bp = (const bf16x8*)(W2b + ((size_t)(ks * 4 + w) * 64 + lane) * 8);
        acc = __builtin_amdgcn_mfma_f32_16x16x32_bf16(af, *bp, acc, 0, 0, 0);
    }
    int col = w * 16 + lrow;
#pragma unroll
    for (int rr = 0; rr < 4; ++rr) {
        int n = nb + lgrp * 4 + rr;
        if (n < N) {
            if (col < HID) z[(size_t)n * HID + col] = bf16r(acc[rr]);
            else           r[(size_t)n * HID + (col - HID)] = acc[rr];
        }
    }
}

// ---------------- x2 = relu(sum_j z[j] + r[v] + b2)  (32-wide bf16 gather, 4x ILP) ----------------
__global__ __launch_bounds__(256) void k_agg_lin(
    const unsigned short* __restrict__ z, const float* __restrict__ r, const float* __restrict__ b,
    const int* __restrict__ off, const unsigned short* __restrict__ srcs,
    unsigned short* __restrict__ xout, int N)
{
    int nl = threadIdx.x >> 5, j = threadIdx.x & 31;
    int n = blockIdx.x * 8 + nl;
    if (n >= N) return;
    float acc = r[n * HID + j] + b[j];
    int beg = off[n], end = off[n + 1];
    int e = beg;
    for (; e + 4 <= end; e += 4) {
        int s0 = srcs[e], s1 = srcs[e + 1], s2 = srcs[e + 2], s3 = srcs[e + 3];
        float v0 = bdec(z[s0 * HID + j]);
        float v1 = bdec(z[s1 * HID + j]);
        float v2 = bdec(z[s2 * HID + j]);
        float v3 = bdec(z[s3 * HID + j]);
        acc += (v0 + v1) + (v2 + v3);
    }
    for (; e < end; ++e)
        acc += bdec(z[srcs[e] * HID + j]);
    xout[n * HID + j] = bf16r(fmaxf(acc, 0.f));
}

// ---------------- fused 32-wide conv (bf16 in/out): agg (4x ILP) + two 32x32 GEMMs + relu ----------------
template <bool MEAN>
__global__ __launch_bounds__(256) void k_conv32(
    const unsigned short* __restrict__ xin, const int* __restrict__ off, const unsigned short* __restrict__ srcs,
    const float* __restrict__ Wl, const float* __restrict__ Wr, const float* __restrict__ b,
    unsigned short* __restrict__ xout, int N)
{
    __shared__ float sagg[8][HID];
    __shared__ float sx[8][HID];
    int nl = threadIdx.x >> 5, j = threadIdx.x & 31;
    int n = blockIdx.x * 8 + nl;
    int nc = min(n, N - 1);
    int beg = off[nc], end = off[nc + 1];
    float acc = 0.f;
    int e = beg;
    for (; e + 4 <= end; e += 4) {
        int s0 = srcs[e], s1 = srcs[e + 1], s2 = srcs[e + 2], s3 = srcs[e + 3];
        float v0 = bdec(xin[s0 * HID + j]);
        float v1 = bdec(xin[s1 * HID + j]);
        float v2 = bdec(xin[s2 * HID + j]);
        float v3 = bdec(xin[s3 * HID + j]);
        acc += (v0 + v1) + (v2 + v3);
    }
    for (; e < end; ++e)
        acc += bdec(xin[srcs[e] * HID + j]);
    if (MEAN) acc /= fmaxf((float)(end - beg), 1.f);
    sagg[nl][j] = acc;
    sx[nl][j] = bdec(xin[nc * HID + j]);
    __syncthreads();
    float o = b[j];
#pragma unroll
    for (int k = 0; k < HID; ++k)
        o += sagg[nl][k] * Wl[k * HID + j] + sx[nl][k] * Wr[k * HID + j];
    o = fmaxf(o, 0.f);
    if (n < N) xout[n * HID + j] = bf16r(o);
}

// ---------------- pool (run-accumulate, PER_BLOCK=128) + last-block MLP head ----------------
__global__ __launch_bounds__(256) void k_pool_head(
    const unsigned short* __restrict__ x4, const int* __restrict__ batch,
    float* __restrict__ gsum, float* __restrict__ gcnt, int N, int* __restrict__ counter,
    const float* __restrict__ fc1W, const float* __restrict__ fc1b,
    const float* __restrict__ fc2W, const float* __restrict__ fc2b,
    float* __restrict__ out)
{
    const int PER_BLOCK = 128;
    int base = blockIdx.x * PER_BLOCK;
    int endn = min(base + PER_BLOCK, N);
    int c = threadIdx.x & 31, no = threadIdx.x >> 5;
    {
        float acc = 0.f, cnt = 0.f;
        int curg = -1;
        for (int n = base + no; n < endn; n += 8) {
            int g = batch[n];
            if (g != curg) {
                if (curg >= 0) {
                    atomicAdd(&gsum[curg * HID + c], acc);
                    if (c == 0) atomicAdd(&gcnt[curg], cnt);
                }
                curg = g; acc = 0.f; cnt = 0.f;
            }
            acc += bdec(x4[n * HID + c]);
            cnt += 1.f;
        }
        if (curg >= 0) {
            atomicAdd(&gsum[curg * HID + c], acc);
            if (c == 0) atomicAdd(&gcnt[curg], cnt);
        }
    }
    __threadfence();
    __shared__ int lastFlag;
    if (threadIdx.x == 0) lastFlag = (atomicAdd(counter, 1) == (int)gridDim.x - 1);
    __syncthreads();
    if (!lastFlag) return;

    __shared__ float g[N_GRAPHS * HID];
    __shared__ float t[N_GRAPHS * HID];
    __shared__ float gc[N_GRAPHS];
    int tid = threadIdx.x;
    if (tid < N_GRAPHS) gc[tid] = atomicAdd(&gcnt[tid], 0.f);
    __syncthreads();
    for (int i = tid; i < N_GRAPHS * HID; i += 256)
        g[i] = atomicAdd(&gsum[i], 0.f) / fmaxf(gc[i >> 5], 1.f);
    __syncthreads();
    for (int i = tid; i < N_GRAPHS * HID; i += 256) {
        int gi = i >> 5, j = i & 31;
        float o = fc1b[j];
#pragma unroll
        for (int k = 0; k < HID; ++k) o += g[gi * HID + k] * fc1W[k * HID + j];
        t[i] = fmaxf(o, 0.f);
    }
    __syncthreads();
    for (int i = tid; i < N_GRAPHS * N_CLASSES; i += 256) {
        int gi = i / N_CLASSES, j = i % N_CLASSES;
        float o = fc2b[j];
#pragma unroll
        for (int k = 0; k < HID; ++k) o += t[gi * HID + k] * fc2W[k * N_CLASSES + j];
        out[i] = o;
    }
}

extern "C" void kernel_launch(void* const* d_in, const int* in_sizes, int n_in,
                              void* d_out, int out_size, void* d_ws, size_t ws_size,
                              hipStream_t stream)
{
    const float* x       = (const float*)d_in[0];
    const int*   eidx    = (const int*)d_in[1];
    const int*   batch   = (const int*)d_in[2];
    const float* gat_W   = (const float*)d_in[3];
    const float* att_s   = (const float*)d_in[4];
    const float* att_d   = (const float*)d_in[5];
    const float* gat_b   = (const float*)d_in[6];
    const float* W2_rel  = (const float*)d_in[7];
    const float* b2      = (const float*)d_in[8];
    const float* W2_root = (const float*)d_in[9];
    const float* W3_l    = (const float*)d_in[10];
    const float* b3      = (const float*)d_in[11];
    const float* W3_r    = (const float*)d_in[12];
    const float* W4_rel  = (const float*)d_in[13];
    const float* b4      = (const float*)d_in[14];
    const float* W4_root = (const float*)d_in[15];
    const float* fc1_W   = (const float*)d_in[16];
    const float* fc1_b   = (const float*)d_in[17];
    const float* fc2_W   = (const float*)d_in[18];
    const float* fc2_b   = (const float*)d_in[19];

    const int N = in_sizes[2];
    const int E = in_sizes[1] / 2;
    const int* esrc = eidx;
    const int* edst = eidx + E;

    char* wsb = (char*)d_ws;
    size_t ofs = 0;
    auto alloc = [&](size_t bytes) {
        char* p = wsb + ofs;
        ofs = (ofs + bytes + 255) & ~(size_t)255;
        return p;
    };
    unsigned short* h   = (unsigned short*)alloc((size_t)N * HC * 2);
    unsigned short* Wb  = (unsigned short*)alloc((size_t)IN_DIM * HC * 2);
    unsigned short* W2b = (unsigned short*)alloc((size_t)HC * 64 * 2);
    float* a_src = (float*)alloc((size_t)N * HEADS * 4);
    float* a_dst = (float*)alloc((size_t)N * HEADS * 4);
    int*   deg   = (int*)alloc((size_t)N * 4);
    int*   off   = (int*)alloc((size_t)(N + 1) * 4);
    unsigned short* rank = (unsigned short*)alloc((size_t)E * 2);
    unsigned short* srcs = (unsigned short*)alloc((size_t)E * 2);
    int*   bsum  = (int*)alloc((size_t)128 * 4);
    unsigned short* zb  = (unsigned short*)alloc((size_t)N * HID * 2);
    float* r     = (float*)alloc((size_t)N * HID * 4);
    unsigned short* x2b = (unsigned short*)alloc((size_t)N * HID * 2);
    unsigned short* x3b = (unsigned short*)alloc((size_t)N * HID * 2);
    unsigned short* x4b = (unsigned short*)alloc((size_t)N * HID * 2);
    float* gsum  = (float*)alloc(N_GRAPHS * HID * 4);
    float* gcnt  = (float*)alloc(N_GRAPHS * 4);
    unsigned* gm = (unsigned*)alloc(HEADS * 4);
    int*  counter = (int*)alloc(4);
    (void)ws_size; (void)n_in; (void)out_size;

    const int nscan = (N + SCAN_CHUNK - 1) / SCAN_CHUNK;
    const int gemmBlocks = (N + 15) / 16;
    const int degBlocks  = (E + 255) / 256;
    const int amaxBlocks = 128;
    const int poolBlocks = (N + 127) / 128;

    k_setup<<<(N + 255) / 256, 256, 0, stream>>>(deg, N, gm, gsum, gcnt, counter,
                                                 gat_W, W2_rel, W2_root, Wb, W2b);
    k_gemm_deg<<<gemmBlocks + degBlocks, 256, 0, stream>>>(
        x, Wb, att_s, att_d, h, a_src, a_dst, N, edst, deg, rank, E, gemmBlocks);
    k_amax_scan<<<amaxBlocks + nscan, 256, 0, stream>>>(a_src, gm, N, deg, bsum, amaxBlocks);
    k_scan_write<<<nscan, SCAN_BLOCK, 0, stream>>>(deg, bsum, off, N);
    k_scatter<<<(E + 255) / 256, 256, 0, stream>>>(esrc, edst, rank, off, srcs, E);
    k_gat_zr<<<gemmBlocks, 256, 0, stream>>>(h, a_src, a_dst, gat_b, off, srcs, gm, W2b, zb, r, N);
    k_agg_lin<<<(N + 7) / 8, 256, 0, stream>>>(zb, r, b2, off, srcs, x2b, N);
    k_conv32<true><<<(N + 7) / 8, 256, 0, stream>>>(x2b, off, srcs, W3_l, W3_r, b3, x3b, N);
    k_conv32<false><<<(N + 7) / 8, 256, 0, stream>>>(x3b, off, srcs, W4_rel, W4_root, b4, x4b, N);
    k_pool_head<<<poolBlocks, 256, 0, stream>>>(x4b, batch, gsum, gcnt, N, counter,
                                                fc1_W, fc1_b, fc2_W, fc2_b, (float*)d_out);
}

// Round 17
// 268.431 us; speedup vs baseline: 1.1405x; 1.0641x over previous
//
#include <hip/hip_runtime.h>

#define IN_DIM 128
#define HID 32
#define HEADS 8
#define HC 256          // HEADS*HID
#define N_GRAPHS 64
#define N_CLASSES 10

#define SCAN_ELEMS 8
#define SCAN_BLOCK 256
#define SCAN_CHUNK (SCAN_ELEMS * SCAN_BLOCK)   // 2048 elements per block

typedef __attribute__((ext_vector_type(8))) short bf16x8;
typedef __attribute__((ext_vector_type(4))) float f32x4;

__device__ __forceinline__ float leaky(float v) { return v > 0.f ? v : 0.2f * v; }

// monotone float<->uint encoding for atomicMax on floats
__device__ __forceinline__ unsigned fenc(float f) {
    unsigned u = __float_as_uint(f);
    return (u & 0x80000000u) ? ~u : (u | 0x80000000u);
}
__device__ __forceinline__ float fdec(unsigned u) {
    return __uint_as_float((u & 0x80000000u) ? (u & 0x7FFFFFFFu) : ~u);
}
// bf16 round-to-nearest-even encode / decode
__device__ __forceinline__ unsigned short bf16r(float f) {
    unsigned u = __float_as_uint(f);
    return (unsigned short)((u + 0x7FFFu + ((u >> 16) & 1u)) >> 16);
}
__device__ __forceinline__ float bdec(unsigned short u) {
    return __uint_as_float(((unsigned)u) << 16);
}

// ---------------- setup: zero deg/gm/gsum/gcnt/counter + bf16 frag-order W prep ----------------
__global__ __launch_bounds__(256) void k_setup(
    int* __restrict__ deg, int N, unsigned* __restrict__ gm,
    float* __restrict__ gsum, float* __restrict__ gcnt, int* __restrict__ counter,
    const float* __restrict__ W, const float* __restrict__ Wrel, const float* __restrict__ Wroot,
    unsigned short* __restrict__ Wb, unsigned short* __restrict__ W2b)
{
    int i = blockIdx.x * 256 + threadIdx.x;
    if (i < N) deg[i] = 0;
    if (i < HEADS) gm[i] = 0u;
    if (i < N_GRAPHS * HID) gsum[i] = 0.f;
    if (i < N_GRAPHS) gcnt[i] = 0.f;
    if (i == 0) *counter = 0;

    if (blockIdx.x < 16) {
        int slot = blockIdx.x * 256 + threadIdx.x;    // 4096 slots (16 ct x 4 ks)
        int lane = slot & 63;
        int ctg  = (slot >> 6) & 15;
        int ks   = slot >> 10;
        int col  = ctg * 16 + (lane & 15);
        int kb   = ks * 32 + (lane >> 4) * 8;
        unsigned short t[8];
#pragma unroll
        for (int j = 0; j < 8; ++j) t[j] = bf16r(W[(size_t)(kb + j) * HC + col]);
        ushort4* dst = (ushort4*)(Wb + (size_t)slot * 8);
        dst[0] = make_ushort4(t[0], t[1], t[2], t[3]);
        dst[1] = make_ushort4(t[4], t[5], t[6], t[7]);
    } else if (blockIdx.x < 24) {
        int slot = (blockIdx.x - 16) * 256 + threadIdx.x;  // 2048 slots (4 ct x 8 ks)
        int lane = slot & 63;
        int ct   = (slot >> 6) & 3;
        int ks   = slot >> 8;
        int col  = ct * 16 + (lane & 15);
        int kb   = ks * 32 + (lane >> 4) * 8;
        const float* src = (col < HID) ? (Wrel + col) : (Wroot + (col - HID));
        unsigned short t[8];
#pragma unroll
        for (int j = 0; j < 8; ++j) t[j] = bf16r(src[(size_t)(kb + j) * HID]);
        ushort4* dst = (ushort4*)(W2b + (size_t)slot * 8);
        dst[0] = make_ushort4(t[0], t[1], t[2], t[3]);
        dst[1] = make_ushort4(t[4], t[5], t[6], t[7]);
    }
}

// ---------------- merged: h = x@gat_W (MFMA, LDS-staged A-tile) || deg+rank ----------------
__global__ __launch_bounds__(256) void k_gemm_deg(
    const float* __restrict__ x, const unsigned short* __restrict__ Wb,
    const float* __restrict__ att_s, const float* __restrict__ att_d,
    unsigned short* __restrict__ h, float* __restrict__ a_src, float* __restrict__ a_dst, int N,
    const int* __restrict__ edst, int* __restrict__ deg, unsigned short* __restrict__ rank,
    int E, int gemmBlocks)
{
    __shared__ unsigned short sxt[16][136];   // bf16 A-tile, 8-ushort pad (<=2-way conflicts)
    __shared__ unsigned short sh[4][16][72];  // output transpose staging
    if (blockIdx.x >= gemmBlocks) {
        int i = (blockIdx.x - gemmBlocks) * 256 + threadIdx.x;
        if (i < E) rank[i] = (unsigned short)atomicAdd(&deg[edst[i]], 1);
        return;
    }
    int w = threadIdx.x >> 6;
    int lane = threadIdx.x & 63;
    int lrow = lane & 15, lgrp = lane >> 4;
    int nb = blockIdx.x * 16;

    {
        int row = threadIdx.x >> 4, col = (threadIdx.x & 15) * 8;
        int n = min(nb + row, N - 1);
        const float* xp = x + (size_t)n * IN_DIM + col;
        float4 a0 = *(const float4*)xp;
        float4 a1 = *(const float4*)(xp + 4);
        *(ushort4*)(&sxt[row][col])     = make_ushort4(bf16r(a0.x), bf16r(a0.y), bf16r(a0.z), bf16r(a0.w));
        *(ushort4*)(&sxt[row][col + 4]) = make_ushort4(bf16r(a1.x), bf16r(a1.y), bf16r(a1.z), bf16r(a1.w));
    }
    __syncthreads();

    f32x4 acc0 = {0.f, 0.f, 0.f, 0.f}, acc1 = acc0, acc2 = acc0, acc3 = acc0;

#pragma unroll
    for (int ks = 0; ks < 4; ++ks) {
        bf16x8 af = *(const bf16x8*)(&sxt[lrow][ks * 32 + lgrp * 8]);
        const bf16x8* bp = (const bf16x8*)(Wb + ((size_t)(ks * 16 + w * 4) * 64 + lane) * 8);
        acc0 = __builtin_amdgcn_mfma_f32_16x16x32_bf16(af, bp[0 * 64], acc0, 0, 0, 0);
        acc1 = __builtin_amdgcn_mfma_f32_16x16x32_bf16(af, bp[1 * 64], acc1, 0, 0, 0);
        acc2 = __builtin_amdgcn_mfma_f32_16x16x32_bf16(af, bp[2 * 64], acc2, 0, 0, 0);
        acc3 = __builtin_amdgcn_mfma_f32_16x16x32_bf16(af, bp[3 * 64], acc3, 0, 0, 0);
    }

    int cbase = w * 64;
#pragma unroll
    for (int r = 0; r < 4; ++r) {
        int lr = lgrp * 4 + r;
        sh[w][lr][lrow]      = bf16r(acc0[r]);
        sh[w][lr][16 + lrow] = bf16r(acc1[r]);
        sh[w][lr][32 + lrow] = bf16r(acc2[r]);
        sh[w][lr][48 + lrow] = bf16r(acc3[r]);
    }
#pragma unroll
    for (int round = 0; round < 2; ++round) {
        int row = (lane >> 3) + round * 8;
        int chunk = lane & 7;
        int n = nb + row;
        if (n < N) {
            uint4 t = *(const uint4*)(&sh[w][row][chunk * 8]);
            *(uint4*)(h + (size_t)n * HC + cbase + chunk * 8) = t;
        }
    }
    int h0 = cbase >> 5, h1 = h0 + 1;
    float as00 = att_s[h0 * HID + lrow], as01 = att_s[h0 * HID + 16 + lrow];
    float as10 = att_s[h1 * HID + lrow], as11 = att_s[h1 * HID + 16 + lrow];
    float ad00 = att_d[h0 * HID + lrow], ad01 = att_d[h0 * HID + 16 + lrow];
    float ad10 = att_d[h1 * HID + lrow], ad11 = att_d[h1 * HID + 16 + lrow];
#pragma unroll
    for (int r = 0; r < 4; ++r) {
        float ps0 = acc0[r] * as00 + acc1[r] * as01;
        float pd0 = acc0[r] * ad00 + acc1[r] * ad01;
        float ps1 = acc2[r] * as10 + acc3[r] * as11;
        float pd1 = acc2[r] * ad10 + acc3[r] * ad11;
#pragma unroll
        for (int d = 1; d < 16; d <<= 1) {
            ps0 += __shfl_xor(ps0, d); pd0 += __shfl_xor(pd0, d);
            ps1 += __shfl_xor(ps1, d); pd1 += __shfl_xor(pd1, d);
        }
        int n = nb + lgrp * 4 + r;
        if (lrow == 0 && n < N) {
            a_src[n * HEADS + h0] = ps0; a_dst[n * HEADS + h0] = pd0;
            a_src[n * HEADS + h1] = ps1; a_dst[n * HEADS + h1] = pd1;
        }
    }
}

// ---------------- merged: per-head max of a_src (float4-vectorized) || scan phase-1 partials ----------------
__global__ __launch_bounds__(256) void k_amax_scan(
    const float* __restrict__ asrc, unsigned* __restrict__ gm, int N,
    const int* __restrict__ deg, int* __restrict__ bsum, int amaxBlocks)
{
    int tid = threadIdx.x;
    if (blockIdx.x < amaxBlocks) {
        __shared__ float sm[4][HEADS];
        float m[HEADS];
#pragma unroll
        for (int hh = 0; hh < HEADS; ++hh) m[hh] = -1e30f;
        int stride = amaxBlocks * 256;
        for (int n = blockIdx.x * 256 + tid; n < N; n += stride) {
            float4 p0 = *(const float4*)(asrc + (size_t)n * HEADS);
            float4 p1 = *(const float4*)(asrc + (size_t)n * HEADS + 4);
            m[0] = fmaxf(m[0], p0.x); m[1] = fmaxf(m[1], p0.y);
            m[2] = fmaxf(m[2], p0.z); m[3] = fmaxf(m[3], p0.w);
            m[4] = fmaxf(m[4], p1.x); m[5] = fmaxf(m[5], p1.y);
            m[6] = fmaxf(m[6], p1.z); m[7] = fmaxf(m[7], p1.w);
        }
#pragma unroll
        for (int hh = 0; hh < HEADS; ++hh)
            for (int d = 1; d < 64; d <<= 1) m[hh] = fmaxf(m[hh], __shfl_xor(m[hh], d));
        int lane = tid & 63, wv = tid >> 6;
        if (lane == 0)
#pragma unroll
            for (int hh = 0; hh < HEADS; ++hh) sm[wv][hh] = m[hh];
        __syncthreads();
        if (tid == 0) {
#pragma unroll
            for (int hh = 0; hh < HEADS; ++hh) {
                float mm = fmaxf(fmaxf(sm[0][hh], sm[1][hh]), fmaxf(sm[2][hh], sm[3][hh]));
                atomicMax(&gm[hh], fenc(mm));
            }
        }
    } else {
        int bid = blockIdx.x - amaxBlocks;
        int base = bid * SCAN_CHUNK + tid * SCAN_ELEMS;
        int s = 0;
#pragma unroll
        for (int i = 0; i < SCAN_ELEMS; ++i) { int idx = base + i; if (idx < N) s += deg[idx]; }
#pragma unroll
        for (int d = 1; d < 64; d <<= 1) s += __shfl_xor(s, d);
        __shared__ int ws[4];
        int lane = tid & 63, wv = tid >> 6;
        if (lane == 0) ws[wv] = s;
        __syncthreads();
        if (tid == 0) bsum[bid] = ws[0] + ws[1] + ws[2] + ws[3];
    }
}

// ---------------- scan write: wave-parallel bsum prefix; writes off + off[N] ----------------
__global__ __launch_bounds__(SCAN_BLOCK) void k_scan_write(
    const int* __restrict__ deg, const int* __restrict__ bsum,
    int* __restrict__ off, int N)
{
    __shared__ int sbpre;
    if (threadIdx.x < 64) {
        int lane = threadIdx.x;
        int bv = (lane < (int)blockIdx.x) ? bsum[lane] : 0;
        for (int d = 1; d < 64; d <<= 1) { int t = __shfl_up(bv, d); if (lane >= d) bv += t; }
        if (lane == 63) sbpre = bv;
    }
    int base = blockIdx.x * SCAN_CHUNK + threadIdx.x * SCAN_ELEMS;
    int dl[SCAN_ELEMS];
    int s = 0;
#pragma unroll
    for (int i = 0; i < SCAN_ELEMS; ++i) {
        int idx = base + i;
        dl[i] = (idx < N) ? deg[idx] : 0;
        s += dl[i];
    }
    int lane = threadIdx.x & 63, wv = threadIdx.x >> 6;
    int v = s;
#pragma unroll
    for (int d = 1; d < 64; d <<= 1) { int t = __shfl_up(v, d); if (lane >= d) v += t; }
    __shared__ int ws[4];
    if (lane == 63) ws[wv] = v;
    __syncthreads();
    int wadd = 0;
    for (int w = 0; w < wv; ++w) wadd += ws[w];
    int run = sbpre + wadd + (v - s);
#pragma unroll
    for (int i = 0; i < SCAN_ELEMS; ++i) {
        int idx = base + i;
        if (idx < N) {
            off[idx] = run;
            run += dl[i];
            if (idx == N - 1) off[N] = run;
        }
    }
}

// ---------------- scatter: pos = off[dst] + rank  (NO atomics) ----------------
__global__ void k_scatter(const int* __restrict__ src, const int* __restrict__ dst,
                          const unsigned short* __restrict__ rank, const int* __restrict__ off,
                          unsigned short* __restrict__ srcs, int E) {
    int i = blockIdx.x * blockDim.x + threadIdx.x;
    if (i < E) srcs[off[dst[i]] + (int)rank[i]] = (unsigned short)src[i];
}

// ---------------- FUSED GAT + zr2: x1 lives only in LDS (single launch); r out bf16 ----------------
__global__ __launch_bounds__(256) void k_gat_zr(
    const unsigned short* __restrict__ h, const float* __restrict__ asrc, const float* __restrict__ adst,
    const float* __restrict__ bias, const int* __restrict__ off, const unsigned short* __restrict__ srcs,
    const unsigned* __restrict__ gm, const unsigned short* __restrict__ W2b,
    unsigned short* __restrict__ z, unsigned short* __restrict__ rb, int N)
{
    __shared__ unsigned short sx1[16][264];
    int w = threadIdx.x >> 6;
    int lane = threadIdx.x & 63;
    int nb = blockIdx.x * 16;
    int head = lane >> 3;
    int c = lane * 4;
    float4 b4 = *(const float4*)(bias + c);
    float gmh = fdec(gm[head]);

    for (int t = 0; t < 4; ++t) {
        int v = min(nb + w * 4 + t, N - 1);
        float ad = adst[v * HEADS + head];
        float asv = asrc[v * HEADS + head];
        float m = leaky(gmh + ad);
        int beg = off[v], end = off[v + 1];

        ushort4 hv = *(const ushort4*)(h + (size_t)v * HC + c);
        float wg = __expf(leaky(asv + ad) - m);
        float zz = wg;
        float acc0 = wg * bdec(hv.x), acc1 = wg * bdec(hv.y), acc2 = wg * bdec(hv.z), acc3 = wg * bdec(hv.w);

        int e = beg;
        for (; e + 4 <= end; e += 4) {
            int s0 = srcs[e + 0], s1 = srcs[e + 1], s2 = srcs[e + 2], s3 = srcs[e + 3];
            float l0 = asrc[s0 * HEADS + head], l1 = asrc[s1 * HEADS + head];
            float l2 = asrc[s2 * HEADS + head], l3 = asrc[s3 * HEADS + head];
            ushort4 g0 = *(const ushort4*)(h + (size_t)s0 * HC + c);
            ushort4 g1 = *(const ushort4*)(h + (size_t)s1 * HC + c);
            ushort4 g2 = *(const ushort4*)(h + (size_t)s2 * HC + c);
            ushort4 g3 = *(const ushort4*)(h + (size_t)s3 * HC + c);
            float w0 = __expf(leaky(l0 + ad) - m);
            float w1 = __expf(leaky(l1 + ad) - m);
            float w2 = __expf(leaky(l2 + ad) - m);
            float w3 = __expf(leaky(l3 + ad) - m);
            zz += (w0 + w1) + (w2 + w3);
            acc0 += w0 * bdec(g0.x) + w1 * bdec(g1.x) + w2 * bdec(g2.x) + w3 * bdec(g3.x);
            acc1 += w0 * bdec(g0.y) + w1 * bdec(g1.y) + w2 * bdec(g2.y) + w3 * bdec(g3.y);
            acc2 += w0 * bdec(g0.z) + w1 * bdec(g1.z) + w2 * bdec(g2.z) + w3 * bdec(g3.z);
            acc3 += w0 * bdec(g0.w) + w1 * bdec(g1.w) + w2 * bdec(g2.w) + w3 * bdec(g3.w);
        }
        for (; e < end; ++e) {
            int s = srcs[e];
            float we = __expf(leaky(asrc[s * HEADS + head] + ad) - m);
            ushort4 hs = *(const ushort4*)(h + (size_t)s * HC + c);
            zz += we;
            acc0 += we * bdec(hs.x); acc1 += we * bdec(hs.y);
            acc2 += we * bdec(hs.z); acc3 += we * bdec(hs.w);
        }
        float inv_z = 1.f / (zz + 1e-16f);
        ushort4 o;
        o.x = bf16r(fmaxf(acc0 * inv_z + b4.x, 0.f));
        o.y = bf16r(fmaxf(acc1 * inv_z + b4.y, 0.f));
        o.z = bf16r(fmaxf(acc2 * inv_z + b4.z, 0.f));
        o.w = bf16r(fmaxf(acc3 * inv_z + b4.w, 0.f));
        *(ushort4*)(&sx1[w * 4 + t][c]) = o;
    }
    __syncthreads();

    int lrow = lane & 15, lgrp = lane >> 4;
    f32x4 acc = {0.f, 0.f, 0.f, 0.f};
#pragma unroll
    for (int ks = 0; ks < 8; ++ks) {
        bf16x8 af = *(const bf16x8*)(&sx1[lrow][ks * 32 + lgrp * 8]);
        const bf16x8* bp = (const bf16x8*)(W2b + ((size_t)(ks * 4 + w) * 64 + lane) * 8);
        acc = __builtin_amdgcn_mfma_f32_16x16x32_bf16(af, *bp, acc, 0, 0, 0);
    }
    int col = w * 16 + lrow;
#pragma unroll
    for (int rr = 0; rr < 4; ++rr) {
        int n = nb + lgrp * 4 + rr;
        if (n < N) {
            if (col < HID) z[(size_t)n * HID + col] = bf16r(acc[rr]);
            else           rb[(size_t)n * HID + (col - HID)] = bf16r(acc[rr]);
        }
    }
}

// ---------------- x2 = relu(sum_j z[j] + r[v] + b2)  (32-wide bf16 gather, 8x ILP) ----------------
__global__ __launch_bounds__(256) void k_agg_lin(
    const unsigned short* __restrict__ z, const unsigned short* __restrict__ rb, const float* __restrict__ b,
    const int* __restrict__ off, const unsigned short* __restrict__ srcs,
    unsigned short* __restrict__ xout, int N)
{
    int nl = threadIdx.x >> 5, j = threadIdx.x & 31;
    int n = blockIdx.x * 8 + nl;
    if (n >= N) return;
    float acc = bdec(rb[n * HID + j]) + b[j];
    int beg = off[n], end = off[n + 1];
    int e = beg;
    for (; e + 8 <= end; e += 8) {
        int s0 = srcs[e], s1 = srcs[e + 1], s2 = srcs[e + 2], s3 = srcs[e + 3];
        int s4 = srcs[e + 4], s5 = srcs[e + 5], s6 = srcs[e + 6], s7 = srcs[e + 7];
        float v0 = bdec(z[s0 * HID + j]), v1 = bdec(z[s1 * HID + j]);
        float v2 = bdec(z[s2 * HID + j]), v3 = bdec(z[s3 * HID + j]);
        float v4 = bdec(z[s4 * HID + j]), v5 = bdec(z[s5 * HID + j]);
        float v6 = bdec(z[s6 * HID + j]), v7 = bdec(z[s7 * HID + j]);
        acc += ((v0 + v1) + (v2 + v3)) + ((v4 + v5) + (v6 + v7));
    }
    for (; e + 4 <= end; e += 4) {
        int s0 = srcs[e], s1 = srcs[e + 1], s2 = srcs[e + 2], s3 = srcs[e + 3];
        float v0 = bdec(z[s0 * HID + j]), v1 = bdec(z[s1 * HID + j]);
        float v2 = bdec(z[s2 * HID + j]), v3 = bdec(z[s3 * HID + j]);
        acc += (v0 + v1) + (v2 + v3);
    }
    for (; e < end; ++e)
        acc += bdec(z[srcs[e] * HID + j]);
    xout[n * HID + j] = bf16r(fmaxf(acc, 0.f));
}

// ---------------- fused 32-wide conv (bf16 in/out): agg (8x ILP) + two 32x32 GEMMs + relu ----------------
template <bool MEAN>
__global__ __launch_bounds__(256) void k_conv32(
    const unsigned short* __restrict__ xin, const int* __restrict__ off, const unsigned short* __restrict__ srcs,
    const float* __restrict__ Wl, const float* __restrict__ Wr, const float* __restrict__ b,
    unsigned short* __restrict__ xout, int N)
{
    __shared__ float sagg[8][HID];
    __shared__ float sx[8][HID];
    int nl = threadIdx.x >> 5, j = threadIdx.x & 31;
    int n = blockIdx.x * 8 + nl;
    int nc = min(n, N - 1);
    int beg = off[nc], end = off[nc + 1];
    float acc = 0.f;
    int e = beg;
    for (; e + 8 <= end; e += 8) {
        int s0 = srcs[e], s1 = srcs[e + 1], s2 = srcs[e + 2], s3 = srcs[e + 3];
        int s4 = srcs[e + 4], s5 = srcs[e + 5], s6 = srcs[e + 6], s7 = srcs[e + 7];
        float v0 = bdec(xin[s0 * HID + j]), v1 = bdec(xin[s1 * HID + j]);
        float v2 = bdec(xin[s2 * HID + j]), v3 = bdec(xin[s3 * HID + j]);
        float v4 = bdec(xin[s4 * HID + j]), v5 = bdec(xin[s5 * HID + j]);
        float v6 = bdec(xin[s6 * HID + j]), v7 = bdec(xin[s7 * HID + j]);
        acc += ((v0 + v1) + (v2 + v3)) + ((v4 + v5) + (v6 + v7));
    }
    for (; e + 4 <= end; e += 4) {
        int s0 = srcs[e], s1 = srcs[e + 1], s2 = srcs[e + 2], s3 = srcs[e + 3];
        float v0 = bdec(xin[s0 * HID + j]), v1 = bdec(xin[s1 * HID + j]);
        float v2 = bdec(xin[s2 * HID + j]), v3 = bdec(xin[s3 * HID + j]);
        acc += (v0 + v1) + (v2 + v3);
    }
    for (; e < end; ++e)
        acc += bdec(xin[srcs[e] * HID + j]);
    if (MEAN) acc /= fmaxf((float)(end - beg), 1.f);
    sagg[nl][j] = acc;
    sx[nl][j] = bdec(xin[nc * HID + j]);
    __syncthreads();
    float o = b[j];
#pragma unroll
    for (int k = 0; k < HID; ++k)
        o += sagg[nl][k] * Wl[k * HID + j] + sx[nl][k] * Wr[k * HID + j];
    o = fmaxf(o, 0.f);
    if (n < N) xout[n * HID + j] = bf16r(o);
}

// ---------------- pool (run-accumulate, PER_BLOCK=512: atomic flushes /4 vs 128) + last-block head ----------------
__global__ __launch_bounds__(256) void k_pool_head(
    const unsigned short* __restrict__ x4, const int* __restrict__ batch,
    float* __restrict__ gsum, float* __restrict__ gcnt, int N, int* __restrict__ counter,
    const float* __restrict__ fc1W, const float* __restrict__ fc1b,
    const float* __restrict__ fc2W, const float* __restrict__ fc2b,
    float* __restrict__ out)
{
    const int PER_BLOCK = 512;
    int base = blockIdx.x * PER_BLOCK;
    int endn = min(base + PER_BLOCK, N);
    int c = threadIdx.x & 31, no = threadIdx.x >> 5;
    {
        float acc = 0.f, cnt = 0.f;
        int curg = -1;
        for (int n = base + no; n < endn; n += 8) {
            int g = batch[n];
            if (g != curg) {
                if (curg >= 0) {
                    atomicAdd(&gsum[curg * HID + c], acc);
                    if (c == 0) atomicAdd(&gcnt[curg], cnt);
                }
                curg = g; acc = 0.f; cnt = 0.f;
            }
            acc += bdec(x4[n * HID + c]);
            cnt += 1.f;
        }
        if (curg >= 0) {
            atomicAdd(&gsum[curg * HID + c], acc);
            if (c == 0) atomicAdd(&gcnt[curg], cnt);
        }
    }
    __threadfence();
    __shared__ int lastFlag;
    if (threadIdx.x == 0) lastFlag = (atomicAdd(counter, 1) == (int)gridDim.x - 1);
    __syncthreads();
    if (!lastFlag) return;

    __shared__ float g[N_GRAPHS * HID];
    __shared__ float t[N_GRAPHS * HID];
    __shared__ float gc[N_GRAPHS];
    int tid = threadIdx.x;
    if (tid < N_GRAPHS) gc[tid] = atomicAdd(&gcnt[tid], 0.f);
    __syncthreads();
    for (int i = tid; i < N_GRAPHS * HID; i += 256)
        g[i] = atomicAdd(&gsum[i], 0.f) / fmaxf(gc[i >> 5], 1.f);
    __syncthreads();
    for (int i = tid; i < N_GRAPHS * HID; i += 256) {
        int gi = i >> 5, j = i & 31;
        float o = fc1b[j];
#pragma unroll
        for (int k = 0; k < HID; ++k) o += g[gi * HID + k] * fc1W[k * HID + j];
        t[i] = fmaxf(o, 0.f);
    }
    __syncthreads();
    for (int i = tid; i < N_GRAPHS * N_CLASSES; i += 256) {
        int gi = i / N_CLASSES, j = i % N_CLASSES;
        float o = fc2b[j];
#pragma unroll
        for (int k = 0; k < HID; ++k) o += t[gi * HID + k] * fc2W[k * N_CLASSES + j];
        out[i] = o;
    }
}

extern "C" void kernel_launch(void* const* d_in, const int* in_sizes, int n_in,
                              void* d_out, int out_size, void* d_ws, size_t ws_size,
                              hipStream_t stream)
{
    const float* x       = (const float*)d_in[0];
    const int*   eidx    = (const int*)d_in[1];
    const int*   batch   = (const int*)d_in[2];
    const float* gat_W   = (const float*)d_in[3];
    const float* att_s   = (const float*)d_in[4];
    const float* att_d   = (const float*)d_in[5];
    const float* gat_b   = (const float*)d_in[6];
    const float* W2_rel  = (const float*)d_in[7];
    const float* b2      = (const float*)d_in[8];
    const float* W2_root = (const float*)d_in[9];
    const float* W3_l    = (const float*)d_in[10];
    const float* b3      = (const float*)d_in[11];
    const float* W3_r    = (const float*)d_in[12];
    const float* W4_rel  = (const float*)d_in[13];
    const float* b4      = (const float*)d_in[14];
    const float* W4_root = (const float*)d_in[15];
    const float* fc1_W   = (const float*)d_in[16];
    const float* fc1_b   = (const float*)d_in[17];
    const float* fc2_W   = (const float*)d_in[18];
    const float* fc2_b   = (const float*)d_in[19];

    const int N = in_sizes[2];
    const int E = in_sizes[1] / 2;
    const int* esrc = eidx;
    const int* edst = eidx + E;

    char* wsb = (char*)d_ws;
    size_t ofs = 0;
    auto alloc = [&](size_t bytes) {
        char* p = wsb + ofs;
        ofs = (ofs + bytes + 255) & ~(size_t)255;
        return p;
    };
    unsigned short* h   = (unsigned short*)alloc((size_t)N * HC * 2);
    unsigned short* Wb  = (unsigned short*)alloc((size_t)IN_DIM * HC * 2);
    unsigned short* W2b = (unsigned short*)alloc((size_t)HC * 64 * 2);
    float* a_src = (float*)alloc((size_t)N * HEADS * 4);
    float* a_dst = (float*)alloc((size_t)N * HEADS * 4);
    int*   deg   = (int*)alloc((size_t)N * 4);
    int*   off   = (int*)alloc((size_t)(N + 1) * 4);
    unsigned short* rank = (unsigned short*)alloc((size_t)E * 2);
    unsigned short* srcs = (unsigned short*)alloc((size_t)E * 2);
    int*   bsum  = (int*)alloc((size_t)128 * 4);
    unsigned short* zb  = (unsigned short*)alloc((size_t)N * HID * 2);
    unsigned short* rb  = (unsigned short*)alloc((size_t)N * HID * 2);
    unsigned short* x2b = (unsigned short*)alloc((size_t)N * HID * 2);
    unsigned short* x3b = (unsigned short*)alloc((size_t)N * HID * 2);
    unsigned short* x4b = (unsigned short*)alloc((size_t)N * HID * 2);
    float* gsum  = (float*)alloc(N_GRAPHS * HID * 4);
    float* gcnt  = (float*)alloc(N_GRAPHS * 4);
    unsigned* gm = (unsigned*)alloc(HEADS * 4);
    int*  counter = (int*)alloc(4);
    (void)ws_size; (void)n_in; (void)out_size;

    const int nscan = (N + SCAN_CHUNK - 1) / SCAN_CHUNK;
    const int gemmBlocks = (N + 15) / 16;
    const int degBlocks  = (E + 255) / 256;
    const int amaxBlocks = 128;
    const int poolBlocks = (N + 511) / 512;

    k_setup<<<(N + 255) / 256, 256, 0, stream>>>(deg, N, gm, gsum, gcnt, counter,
                                                 gat_W, W2_rel, W2_root, Wb, W2b);
    k_gemm_deg<<<gemmBlocks + degBlocks, 256, 0, stream>>>(
        x, Wb, att_s, att_d, h, a_src, a_dst, N, edst, deg, rank, E, gemmBlocks);
    k_amax_scan<<<amaxBlocks + nscan, 256, 0, stream>>>(a_src, gm, N, deg, bsum, amaxBlocks);
    k_scan_write<<<nscan, SCAN_BLOCK, 0, stream>>>(deg, bsum, off, N);
    k_scatter<<<(E + 255) / 256, 256, 0, stream>>>(esrc, edst, rank, off, srcs, E);
    k_gat_zr<<<gemmBlocks, 256, 0, stream>>>(h, a_src, a_dst, gat_b, off, srcs, gm, W2b, zb, rb, N);
    k_agg_lin<<<(N + 7) / 8, 256, 0, stream>>>(zb, rb, b2, off, srcs, x2b, N);
    k_conv32<true><<<(N + 7) / 8, 256, 0, stream>>>(x2b, off, srcs, W3_l, W3_r, b3, x3b, N);
    k_conv32<false><<<(N + 7) / 8, 256, 0, stream>>>(x3b, off, srcs, W4_rel, W4_root, b4, x4b, N);
    k_pool_head<<<poolBlocks, 256, 0, stream>>>(x4b, batch, gsum, gcnt, N, counter,
                                                fc1_W, fc1_b, fc2_W, fc2_b, (float*)d_out);
}